// Round 5
// baseline (1405.389 us; speedup 1.0000x reference)
//
#include <hip/hip_runtime.h>

#define D 64
#define ED 16

// ---------------------------------------------------------------------------
// Probe: is edge_index int64 or int32?  flag[0] = 1 -> int64, 0 -> int32.
// ---------------------------------------------------------------------------
__global__ void detect_idx64_kernel(const int* __restrict__ idx32, int* __restrict__ flag)
{
    __shared__ int any;
    if (threadIdx.x == 0) any = 0;
    __syncthreads();
    int v = 0;
    for (int i = threadIdx.x; i < 8192; i += blockDim.x)
        v |= idx32[2 * i + 1];
    if (v) atomicOr(&any, 1);
    __syncthreads();
    if (threadIdx.x == 0) flag[0] = (any == 0) ? 1 : 0;
}

__device__ __forceinline__ int load_idx(const void* p, size_t i, int is64)
{
    return is64 ? (int)((const long long*)p)[i] : ((const int*)p)[i];
}

// ---------------------------------------------------------------------------
// CSR build step 1: per-destination degree count (1 int atomic per edge).
// ---------------------------------------------------------------------------
__global__ void __launch_bounds__(256)
count_kernel(const void* __restrict__ edge_index, const int* __restrict__ flag,
             int* __restrict__ cnt, int n_edges)
{
    const int is64 = flag[0];
    const int stride = gridDim.x * blockDim.x;
    for (int e = blockIdx.x * blockDim.x + threadIdx.x; e < n_edges; e += stride) {
        int dst = load_idx(edge_index, (size_t)n_edges + e, is64);
        atomicAdd(&cnt[dst], 1);
    }
}

// ---------------------------------------------------------------------------
// CSR build step 2: two-level exclusive scan of cnt -> offs.
// ---------------------------------------------------------------------------
__global__ void scan1_kernel(const int* __restrict__ cnt, int* __restrict__ offs,
                             int* __restrict__ bsum, int n)
{
    __shared__ int sd[256];
    const int t = threadIdx.x;
    const int i = blockIdx.x * 256 + t;
    int v = (i < n) ? cnt[i] : 0;
    sd[t] = v;
    __syncthreads();
    for (int off = 1; off < 256; off <<= 1) {
        int add = (t >= off) ? sd[t - off] : 0;
        __syncthreads();
        sd[t] += add;
        __syncthreads();
    }
    if (i < n) offs[i] = sd[t] - v;          // exclusive
    if (t == 255) bsum[blockIdx.x] = sd[t];  // block total
}

__global__ void scan2_kernel(int* __restrict__ bsum, int nb)
{
    __shared__ int sd[512];
    const int t = threadIdx.x;
    int v = (t < nb) ? bsum[t] : 0;
    sd[t] = v;
    __syncthreads();
    for (int off = 1; off < 512; off <<= 1) {
        int add = (t >= off) ? sd[t - off] : 0;
        __syncthreads();
        sd[t] += add;
        __syncthreads();
    }
    if (t < nb) bsum[t] = sd[t] - v;         // exclusive block offsets
}

__global__ void scan3_kernel(int* __restrict__ offs, int* __restrict__ cursor,
                             const int* __restrict__ bsum, int n)
{
    const int i = blockIdx.x * 256 + threadIdx.x;
    if (i < n) {
        int v = offs[i] + bsum[i >> 8];
        offs[i]   = v;
        cursor[i] = v;
    }
}

// ---------------------------------------------------------------------------
// CSR build step 3: scatter (src, eid) pairs to sorted-by-dst positions.
// ---------------------------------------------------------------------------
__global__ void __launch_bounds__(256)
scatter_kernel(const void* __restrict__ edge_index, const int* __restrict__ flag,
               int* __restrict__ cursor, int2* __restrict__ pair, int n_edges)
{
    const int is64 = flag[0];
    const int stride = gridDim.x * blockDim.x;
    for (int e = blockIdx.x * blockDim.x + threadIdx.x; e < n_edges; e += stride) {
        int src = load_idx(edge_index, e, is64);
        int dst = load_idx(edge_index, (size_t)n_edges + e, is64);
        int pos = atomicAdd(&cursor[dst], 1);
        pair[pos] = make_int2(src, e);
    }
}

// ---------------------------------------------------------------------------
// Gather-reduce: one wave per node, 16 edges per iteration for MLP.
//   agg_mean[i] = ( sum_e x[src_e] + (sum_e ea[e]) @ W_e + deg*b_e ) / max(deg,1)
// ---------------------------------------------------------------------------
__global__ void __launch_bounds__(256)
reduce_kernel(const float* __restrict__ x,
              const float* __restrict__ edge_attr,
              const float* __restrict__ W_e,
              const float* __restrict__ b_e,
              const int2* __restrict__ pair,
              const int* __restrict__ offs,
              const int* __restrict__ cnt,
              float* __restrict__ agg,
              int n_nodes)
{
    __shared__ float We[ED * D];
    __shared__ float be[D];
    for (int i = threadIdx.x; i < ED * D; i += blockDim.x) We[i] = W_e[i];
    if (threadIdx.x < D) be[threadIdx.x] = b_e[threadIdx.x];
    __syncthreads();

    const int lane = threadIdx.x & 63;
    const int wid  = threadIdx.x >> 6;
    const int node = blockIdx.x * 4 + wid;
    if (node >= n_nodes) return;

    const int beg = offs[node];
    const int deg = cnt[node];
    const int sub = lane >> 4;
    const int k16 = lane & 15;

    float xs  = 0.0f;   // per-lane component of sum x[src]
    float eas = 0.0f;   // per-(lane&15) component of sum edge_attr

    for (int j0 = 0; j0 < deg; j0 += 16) {
        const int nb = min(16, deg - j0);       // wave-uniform
        int2 p = make_int2(0, 0);
        if (lane < nb) p = pair[beg + j0 + lane];

        // 16 independent x-row gathers
        float t[16];
        #pragma unroll
        for (int m = 0; m < 16; ++m) {
            int s = __shfl(p.x, m);
            t[m] = (m < nb) ? x[(size_t)s * D + lane] : 0.0f;
        }

        // 4 independent edge_attr gathers per lane (edge m = sub + 4*mm)
        #pragma unroll
        for (int mm = 0; mm < 4; ++mm) {
            int m = sub + 4 * mm;
            int eid = __shfl(p.y, m);
            if (m < nb) eas += edge_attr[(size_t)eid * ED + k16];
        }

        #pragma unroll
        for (int m = 0; m < 16; ++m) xs += t[m];
    }
    eas += __shfl_xor(eas, 16);
    eas += __shfl_xor(eas, 32);

    float acc = xs + (float)deg * be[lane];
    #pragma unroll
    for (int k = 0; k < 16; ++k)
        acc += __shfl(eas, k) * We[k * D + lane];

    const float s = 1.0f / fmaxf((float)deg, 1.0f);
    agg[(size_t)node * D + lane] = acc * s;
}

// ---------------------------------------------------------------------------
// Fallback edge phase (atomic scatter) — used only if ws_size is too small.
// ---------------------------------------------------------------------------
__global__ void __launch_bounds__(256)
edge_scatter_kernel(const float* __restrict__ x,
                    const float* __restrict__ edge_attr,
                    const float* __restrict__ W_e,
                    const float* __restrict__ b_e,
                    const void* __restrict__ edge_index,
                    const int* __restrict__ flag,
                    float* __restrict__ agg,
                    float* __restrict__ cnt,
                    int n_edges)
{
    __shared__ float We[ED * D];
    __shared__ float be[D];
    for (int i = threadIdx.x; i < ED * D; i += blockDim.x) We[i] = W_e[i];
    if (threadIdx.x < D) be[threadIdx.x] = b_e[threadIdx.x];
    __syncthreads();

    const int is64 = flag[0];
    const int lane = threadIdx.x & 63;
    const int wid  = threadIdx.x >> 6;
    const int estr = gridDim.x * 4;

    for (int e = blockIdx.x * 4 + wid; e < n_edges; e += estr) {
        int src = load_idx(edge_index, e, is64);
        int dst = load_idx(edge_index, (size_t)n_edges + e, is64);
        const float4* ea = (const float4*)(edge_attr + (size_t)e * ED);
        float4 e0 = ea[0], e1 = ea[1], e2 = ea[2], e3 = ea[3];

        float m = be[lane] + x[(size_t)src * D + lane];
        m += e0.x * We[ 0*D + lane] + e0.y * We[ 1*D + lane]
           + e0.z * We[ 2*D + lane] + e0.w * We[ 3*D + lane];
        m += e1.x * We[ 4*D + lane] + e1.y * We[ 5*D + lane]
           + e1.z * We[ 6*D + lane] + e1.w * We[ 7*D + lane];
        m += e2.x * We[ 8*D + lane] + e2.y * We[ 9*D + lane]
           + e2.z * We[10*D + lane] + e2.w * We[11*D + lane];
        m += e3.x * We[12*D + lane] + e3.y * We[13*D + lane]
           + e3.z * We[14*D + lane] + e3.w * We[15*D + lane];

        atomicAdd(&agg[(size_t)dst * D + lane], m);
        if (lane == 0) atomicAdd(&cnt[dst], 1.0f);
    }
}

__global__ void divide_kernel(float* __restrict__ agg, const float* __restrict__ cnt, int n_nodes)
{
    const int i = blockIdx.x * 256 + threadIdx.x;
    if (i < n_nodes * D) {
        float c = cnt[i >> 6];
        agg[i] *= 1.0f / fmaxf(c, 1.0f);
    }
}

// ---------------------------------------------------------------------------
// Node phase as one GEMM:  out = [agg | x] @ [W_l ; W_r] + b_l
//   M = n_nodes, K = 128 (64 agg + 64 x), N = 64.  f32 vector FMA.
// Tile: BM=128 nodes x BN=64 cols per 256-thread block, BK=32 (4 K-steps:
// s=0,1 read agg rows, s=2,3 read x rows).  A-tile staged TRANSPOSED in LDS
// (AT[32][132]; pad->16B-aligned b128 rows, read banks 4kk+{0,8,16,24} ok).
// Per-thread micro-tile 8 nodes x 4 cols: per kk, 2x b128(A) + 1x b128(W)
// + 32 independent FMAs -> FMA-bound.
// In-place safe: block reads all its agg rows (steps 0-1) before epilogue
// store; blocks own disjoint node ranges.  (agg/out NOT __restrict: alias.)
// ---------------------------------------------------------------------------
#define BM 128
#define BK 32
#define ATP 132   // padded row length (dwords): 132*4B % 16B == 0

__global__ void __launch_bounds__(256)
node_gemm_kernel(const float* x,
                 const float* agg,                // == out (in-place)
                 const float* __restrict__ W_l,
                 const float* __restrict__ b_l,
                 const float* __restrict__ W_r,
                 float* out,
                 int n_nodes)
{
    __shared__ float AT[BK][ATP];     // 16.5 KB
    __shared__ float Wt[BK][D];       // 8 KB

    const int t   = threadIdx.x;
    const int to  = t & 15;           // col group: cols 4*to .. 4*to+3
    const int tm  = t >> 4;           // node group: nodes 8*tm .. 8*tm+7
    const int base = blockIdx.x * BM;

    float acc[8][4];
    #pragma unroll
    for (int n = 0; n < 8; ++n)
        #pragma unroll
        for (int c = 0; c < 4; ++c) acc[n][c] = 0.0f;

    #pragma unroll
    for (int s = 0; s < 4; ++s) {
        const float* src  = (s < 2) ? agg : x;
        const float* Wsrc = (s < 2) ? W_l : W_r;
        const int    k0   = (s & 1) * BK;

        __syncthreads();   // previous step's LDS reads done before overwrite

        // stage A^T: 128 nodes x 32 k  (4 float4 loads / thread)
        #pragma unroll
        for (int q = 0; q < 4; ++q) {
            const int idx  = t + 256 * q;       // 0..1023
            const int node = idx >> 3;          // 0..127
            const int kq   = (idx & 7) * 4;     // 0,4,..,28
            float4 v = make_float4(0.f, 0.f, 0.f, 0.f);
            if (base + node < n_nodes)
                v = *(const float4*)(src + (size_t)(base + node) * D + k0 + kq);
            AT[kq + 0][node] = v.x;
            AT[kq + 1][node] = v.y;
            AT[kq + 2][node] = v.z;
            AT[kq + 3][node] = v.w;
        }
        // stage W: 32 rows x 64 cols  (2 float4 loads / thread)
        #pragma unroll
        for (int q = 0; q < 2; ++q) {
            const int idx = t + 256 * q;        // 0..511
            const int kk  = idx >> 4;           // 0..31
            const int cq  = (idx & 15) * 4;
            *(float4*)&Wt[kk][cq] = *(const float4*)(Wsrc + (size_t)(k0 + kk) * D + cq);
        }
        __syncthreads();

        #pragma unroll
        for (int kk = 0; kk < BK; ++kk) {
            float4 a0 = *(const float4*)&AT[kk][tm * 8];
            float4 a1 = *(const float4*)&AT[kk][tm * 8 + 4];
            float4 w  = *(const float4*)&Wt[kk][to * 4];
            acc[0][0] += a0.x * w.x; acc[0][1] += a0.x * w.y; acc[0][2] += a0.x * w.z; acc[0][3] += a0.x * w.w;
            acc[1][0] += a0.y * w.x; acc[1][1] += a0.y * w.y; acc[1][2] += a0.y * w.z; acc[1][3] += a0.y * w.w;
            acc[2][0] += a0.z * w.x; acc[2][1] += a0.z * w.y; acc[2][2] += a0.z * w.z; acc[2][3] += a0.z * w.w;
            acc[3][0] += a0.w * w.x; acc[3][1] += a0.w * w.y; acc[3][2] += a0.w * w.z; acc[3][3] += a0.w * w.w;
            acc[4][0] += a1.x * w.x; acc[4][1] += a1.x * w.y; acc[4][2] += a1.x * w.z; acc[4][3] += a1.x * w.w;
            acc[5][0] += a1.y * w.x; acc[5][1] += a1.y * w.y; acc[5][2] += a1.y * w.z; acc[5][3] += a1.y * w.w;
            acc[6][0] += a1.z * w.x; acc[6][1] += a1.z * w.y; acc[6][2] += a1.z * w.z; acc[6][3] += a1.z * w.w;
            acc[7][0] += a1.w * w.x; acc[7][1] += a1.w * w.y; acc[7][2] += a1.w * w.z; acc[7][3] += a1.w * w.w;
        }
    }

    // epilogue: add bias, store (coalesced float4; reads of agg all done)
    const float4 bb = *(const float4*)(b_l + to * 4);
    #pragma unroll
    for (int n = 0; n < 8; ++n) {
        const int node = base + tm * 8 + n;
        if (node < n_nodes) {
            float4 r = make_float4(acc[n][0] + bb.x, acc[n][1] + bb.y,
                                   acc[n][2] + bb.z, acc[n][3] + bb.w);
            *(float4*)(out + (size_t)node * D + to * 4) = r;
        }
    }
}

// ---------------------------------------------------------------------------
extern "C" void kernel_launch(void* const* d_in, const int* in_sizes, int n_in,
                              void* d_out, int out_size, void* d_ws, size_t ws_size,
                              hipStream_t stream)
{
    const float* x         = (const float*)d_in[0];
    const float* edge_attr = (const float*)d_in[1];
    const float* W_e       = (const float*)d_in[2];
    const float* b_e       = (const float*)d_in[3];
    const float* W_l       = (const float*)d_in[4];
    const float* b_l       = (const float*)d_in[5];
    const float* W_r       = (const float*)d_in[6];
    const void*  edge_index= d_in[7];

    const int n_nodes = in_sizes[0] / D;
    const int n_edges = in_sizes[1] / ED;

    float* out = (float*)d_out;

    // workspace layout (bytes)
    const size_t n_align = ((size_t)n_nodes + 255) & ~(size_t)255;
    const int    NB      = (n_nodes + 255) / 256;       // scan blocks
    const size_t o_flag  = 0;
    const size_t o_cnt   = 512;
    const size_t o_offs  = o_cnt  + n_align * 4;
    const size_t o_cur   = o_offs + n_align * 4;
    const size_t o_bsum  = o_cur  + n_align * 4;
    const size_t o_pair  = (o_bsum + (size_t)NB * 4 + 255) & ~(size_t)255;
    const size_t need    = o_pair + (size_t)n_edges * 8;

    int* flag = (int*)((char*)d_ws + o_flag);

    detect_idx64_kernel<<<1, 256, 0, stream>>>((const int*)edge_index, flag);

    if (need <= ws_size && NB <= 512) {
        int*  cnt    = (int*)((char*)d_ws + o_cnt);
        int*  offs   = (int*)((char*)d_ws + o_offs);
        int*  cursor = (int*)((char*)d_ws + o_cur);
        int*  bsum   = (int*)((char*)d_ws + o_bsum);
        int2* pair   = (int2*)((char*)d_ws + o_pair);

        hipMemsetAsync(cnt, 0, n_align * 4, stream);

        count_kernel<<<2048, 256, 0, stream>>>(edge_index, flag, cnt, n_edges);
        scan1_kernel<<<NB, 256, 0, stream>>>(cnt, offs, bsum, n_nodes);
        scan2_kernel<<<1, 512, 0, stream>>>(bsum, NB);
        scan3_kernel<<<NB, 256, 0, stream>>>(offs, cursor, bsum, n_nodes);
        scatter_kernel<<<2048, 256, 0, stream>>>(edge_index, flag, cursor, pair, n_edges);
        reduce_kernel<<<(n_nodes + 3) / 4, 256, 0, stream>>>(
            x, edge_attr, W_e, b_e, pair, offs, cnt, out, n_nodes);
    } else {
        // fallback: atomic scatter path
        float* cntf = (float*)((char*)d_ws + o_cnt);
        hipMemsetAsync(out, 0, (size_t)out_size * sizeof(float), stream);
        hipMemsetAsync(cntf, 0, (size_t)n_nodes * sizeof(float), stream);
        edge_scatter_kernel<<<4096, 256, 0, stream>>>(
            x, edge_attr, W_e, b_e, edge_index, flag, out, cntf, n_edges);
        divide_kernel<<<(n_nodes * D + 255) / 256, 256, 0, stream>>>(out, cntf, n_nodes);
    }

    node_gemm_kernel<<<(n_nodes + BM - 1) / BM, 256, 0, stream>>>(
        x, out, W_l, b_l, W_r, out, n_nodes);
}

// Round 6
// 248.789 us; speedup vs baseline: 5.6489x; 5.6489x over previous
//
#include <hip/hip_runtime.h>

#define D 64
#define ED 16

// ---------------------------------------------------------------------------
// Probe: is edge_index int64 or int32?  flag[0] = 1 -> int64, 0 -> int32.
// ---------------------------------------------------------------------------
__global__ void detect_idx64_kernel(const int* __restrict__ idx32, int* __restrict__ flag)
{
    __shared__ int any;
    if (threadIdx.x == 0) any = 0;
    __syncthreads();
    int v = 0;
    for (int i = threadIdx.x; i < 8192; i += blockDim.x)
        v |= idx32[2 * i + 1];
    if (v) atomicOr(&any, 1);
    __syncthreads();
    if (threadIdx.x == 0) flag[0] = (any == 0) ? 1 : 0;
}

__device__ __forceinline__ int load_idx(const void* p, size_t i, int is64)
{
    return is64 ? (int)((const long long*)p)[i] : ((const int*)p)[i];
}

// ---------------------------------------------------------------------------
// CSR build step 1: per-destination degree count (1 int atomic per edge).
// ---------------------------------------------------------------------------
__global__ void __launch_bounds__(256)
count_kernel(const void* __restrict__ edge_index, const int* __restrict__ flag,
             int* __restrict__ cnt, int n_edges)
{
    const int is64 = flag[0];
    const int stride = gridDim.x * blockDim.x;
    for (int e = blockIdx.x * blockDim.x + threadIdx.x; e < n_edges; e += stride) {
        int dst = load_idx(edge_index, (size_t)n_edges + e, is64);
        atomicAdd(&cnt[dst], 1);
    }
}

// ---------------------------------------------------------------------------
// CSR build step 2: two-level exclusive scan of cnt -> offs.
// ---------------------------------------------------------------------------
__global__ void scan1_kernel(const int* __restrict__ cnt, int* __restrict__ offs,
                             int* __restrict__ bsum, int n)
{
    __shared__ int sd[256];
    const int t = threadIdx.x;
    const int i = blockIdx.x * 256 + t;
    int v = (i < n) ? cnt[i] : 0;
    sd[t] = v;
    __syncthreads();
    for (int off = 1; off < 256; off <<= 1) {
        int add = (t >= off) ? sd[t - off] : 0;
        __syncthreads();
        sd[t] += add;
        __syncthreads();
    }
    if (i < n) offs[i] = sd[t] - v;          // exclusive
    if (t == 255) bsum[blockIdx.x] = sd[t];  // block total
}

__global__ void scan2_kernel(int* __restrict__ bsum, int nb)
{
    __shared__ int sd[512];
    const int t = threadIdx.x;
    int v = (t < nb) ? bsum[t] : 0;
    sd[t] = v;
    __syncthreads();
    for (int off = 1; off < 512; off <<= 1) {
        int add = (t >= off) ? sd[t - off] : 0;
        __syncthreads();
        sd[t] += add;
        __syncthreads();
    }
    if (t < nb) bsum[t] = sd[t] - v;         // exclusive block offsets
}

__global__ void scan3_kernel(int* __restrict__ offs, int* __restrict__ cursor,
                             const int* __restrict__ bsum, int n)
{
    const int i = blockIdx.x * 256 + threadIdx.x;
    if (i < n) {
        int v = offs[i] + bsum[i >> 8];
        offs[i]   = v;
        cursor[i] = v;
    }
}

// ---------------------------------------------------------------------------
// CSR build step 3: scatter (src, eid) pairs to sorted-by-dst positions.
// ---------------------------------------------------------------------------
__global__ void __launch_bounds__(256)
scatter_kernel(const void* __restrict__ edge_index, const int* __restrict__ flag,
               int* __restrict__ cursor, int2* __restrict__ pair, int n_edges)
{
    const int is64 = flag[0];
    const int stride = gridDim.x * blockDim.x;
    for (int e = blockIdx.x * blockDim.x + threadIdx.x; e < n_edges; e += stride) {
        int src = load_idx(edge_index, e, is64);
        int dst = load_idx(edge_index, (size_t)n_edges + e, is64);
        int pos = atomicAdd(&cursor[dst], 1);
        pair[pos] = make_int2(src, e);
    }
}

// ---------------------------------------------------------------------------
// Gather-reduce: one wave per node, 16 edges per iteration for MLP.
//   agg_mean[i] = ( sum_e x[src_e] + (sum_e ea[e]) @ W_e + deg*b_e ) / max(deg,1)
// ---------------------------------------------------------------------------
__global__ void __launch_bounds__(256)
reduce_kernel(const float* __restrict__ x,
              const float* __restrict__ edge_attr,
              const float* __restrict__ W_e,
              const float* __restrict__ b_e,
              const int2* __restrict__ pair,
              const int* __restrict__ offs,
              const int* __restrict__ cnt,
              float* __restrict__ agg,
              int n_nodes)
{
    __shared__ float We[ED * D];
    __shared__ float be[D];
    for (int i = threadIdx.x; i < ED * D; i += blockDim.x) We[i] = W_e[i];
    if (threadIdx.x < D) be[threadIdx.x] = b_e[threadIdx.x];
    __syncthreads();

    const int lane = threadIdx.x & 63;
    const int wid  = threadIdx.x >> 6;
    const int node = blockIdx.x * 4 + wid;
    if (node >= n_nodes) return;

    const int beg = offs[node];
    const int deg = cnt[node];
    const int sub = lane >> 4;
    const int k16 = lane & 15;

    float xs  = 0.0f;   // per-lane component of sum x[src]
    float eas = 0.0f;   // per-(lane&15) component of sum edge_attr

    for (int j0 = 0; j0 < deg; j0 += 16) {
        const int nb = min(16, deg - j0);       // wave-uniform
        int2 p = make_int2(0, 0);
        if (lane < nb) p = pair[beg + j0 + lane];

        // 16 independent x-row gathers
        float t[16];
        #pragma unroll
        for (int m = 0; m < 16; ++m) {
            int s = __shfl(p.x, m);
            t[m] = (m < nb) ? x[(size_t)s * D + lane] : 0.0f;
        }

        // 4 independent edge_attr gathers per lane (edge m = sub + 4*mm)
        #pragma unroll
        for (int mm = 0; mm < 4; ++mm) {
            int m = sub + 4 * mm;
            int eid = __shfl(p.y, m);
            if (m < nb) eas += edge_attr[(size_t)eid * ED + k16];
        }

        #pragma unroll
        for (int m = 0; m < 16; ++m) xs += t[m];
    }
    eas += __shfl_xor(eas, 16);
    eas += __shfl_xor(eas, 32);

    float acc = xs + (float)deg * be[lane];
    #pragma unroll
    for (int k = 0; k < 16; ++k)
        acc += __shfl(eas, k) * We[k * D + lane];

    const float s = 1.0f / fmaxf((float)deg, 1.0f);
    agg[(size_t)node * D + lane] = acc * s;
}

// ---------------------------------------------------------------------------
// Fallback edge phase (atomic scatter) — used only if ws_size is too small.
// ---------------------------------------------------------------------------
__global__ void __launch_bounds__(256)
edge_scatter_kernel(const float* __restrict__ x,
                    const float* __restrict__ edge_attr,
                    const float* __restrict__ W_e,
                    const float* __restrict__ b_e,
                    const void* __restrict__ edge_index,
                    const int* __restrict__ flag,
                    float* __restrict__ agg,
                    float* __restrict__ cnt,
                    int n_edges)
{
    __shared__ float We[ED * D];
    __shared__ float be[D];
    for (int i = threadIdx.x; i < ED * D; i += blockDim.x) We[i] = W_e[i];
    if (threadIdx.x < D) be[threadIdx.x] = b_e[threadIdx.x];
    __syncthreads();

    const int is64 = flag[0];
    const int lane = threadIdx.x & 63;
    const int wid  = threadIdx.x >> 6;
    const int estr = gridDim.x * 4;

    for (int e = blockIdx.x * 4 + wid; e < n_edges; e += estr) {
        int src = load_idx(edge_index, e, is64);
        int dst = load_idx(edge_index, (size_t)n_edges + e, is64);
        const float4* ea = (const float4*)(edge_attr + (size_t)e * ED);
        float4 e0 = ea[0], e1 = ea[1], e2 = ea[2], e3 = ea[3];

        float m = be[lane] + x[(size_t)src * D + lane];
        m += e0.x * We[ 0*D + lane] + e0.y * We[ 1*D + lane]
           + e0.z * We[ 2*D + lane] + e0.w * We[ 3*D + lane];
        m += e1.x * We[ 4*D + lane] + e1.y * We[ 5*D + lane]
           + e1.z * We[ 6*D + lane] + e1.w * We[ 7*D + lane];
        m += e2.x * We[ 8*D + lane] + e2.y * We[ 9*D + lane]
           + e2.z * We[10*D + lane] + e2.w * We[11*D + lane];
        m += e3.x * We[12*D + lane] + e3.y * We[13*D + lane]
           + e3.z * We[14*D + lane] + e3.w * We[15*D + lane];

        atomicAdd(&agg[(size_t)dst * D + lane], m);
        if (lane == 0) atomicAdd(&cnt[dst], 1.0f);
    }
}

__global__ void divide_kernel(float* __restrict__ agg, const float* __restrict__ cnt, int n_nodes)
{
    const int i = blockIdx.x * 256 + threadIdx.x;
    if (i < n_nodes * D) {
        float c = cnt[i >> 6];
        agg[i] *= 1.0f / fmaxf(c, 1.0f);
    }
}

// ---------------------------------------------------------------------------
// Node phase as one GEMM:  out = [agg | x] @ [W_l ; W_r] + b_l
//   M = n_nodes, K = 128 (64 agg + 64 x), N = 64.  f32 vector FMA.
// Tile: BM=128 nodes x BN=64 cols per 256-thread block, BK=32 (4 K-steps:
// s=0,1 read agg rows, s=2,3 read x rows).  A-tile staged TRANSPOSED in LDS.
// REGISTER DISCIPLINE (round-5 lesson): s-loop rolled (unroll 1), kk-loop
// unroll 4 only, __launch_bounds__(256,4) caps VGPR at 128 — the round-5
// full unroll hoisted 96 b128 loads, spilled to scratch (1.9 GB FETCH,
// 1160 us).  Per-thread micro-tile 8 nodes x 4 cols.
// In-place safe: block reads all its agg rows before epilogue store; blocks
// own disjoint node ranges.  (agg/out NOT __restrict: they alias.)
// ---------------------------------------------------------------------------
#define BM 128
#define BK 32
#define ATP 132   // padded row length (dwords): 132*4B % 16B == 0

__global__ void __launch_bounds__(256, 4)
node_gemm_kernel(const float* x,
                 const float* agg,                // == out (in-place)
                 const float* __restrict__ W_l,
                 const float* __restrict__ b_l,
                 const float* __restrict__ W_r,
                 float* out,
                 int n_nodes)
{
    __shared__ float AT[BK][ATP];     // 16.5 KB
    __shared__ float Wt[BK][D];       // 8 KB

    const int t   = threadIdx.x;
    const int to  = t & 15;           // col group: cols 4*to .. 4*to+3
    const int tm  = t >> 4;           // node group: nodes 8*tm .. 8*tm+7
    const int base = blockIdx.x * BM;

    float acc[8][4];
    #pragma unroll
    for (int n = 0; n < 8; ++n)
        #pragma unroll
        for (int c = 0; c < 4; ++c) acc[n][c] = 0.0f;

    #pragma unroll 1
    for (int s = 0; s < 4; ++s) {
        const float* src  = (s < 2) ? agg : x;
        const float* Wsrc = (s < 2) ? W_l : W_r;
        const int    k0   = (s & 1) * BK;

        __syncthreads();   // previous step's LDS reads done before overwrite

        // stage A^T: 128 nodes x 32 k  (4 float4 loads / thread)
        #pragma unroll
        for (int q = 0; q < 4; ++q) {
            const int idx  = t + 256 * q;       // 0..1023
            const int node = idx >> 3;          // 0..127
            const int kq   = (idx & 7) * 4;     // 0,4,..,28
            float4 v = make_float4(0.f, 0.f, 0.f, 0.f);
            if (base + node < n_nodes)
                v = *(const float4*)(src + (size_t)(base + node) * D + k0 + kq);
            AT[kq + 0][node] = v.x;
            AT[kq + 1][node] = v.y;
            AT[kq + 2][node] = v.z;
            AT[kq + 3][node] = v.w;
        }
        // stage W: 32 rows x 64 cols  (2 float4 loads / thread)
        #pragma unroll
        for (int q = 0; q < 2; ++q) {
            const int idx = t + 256 * q;        // 0..511
            const int kk  = idx >> 4;           // 0..31
            const int cq  = (idx & 15) * 4;
            *(float4*)&Wt[kk][cq] = *(const float4*)(Wsrc + (size_t)(k0 + kk) * D + cq);
        }
        __syncthreads();

        #pragma unroll 4
        for (int kk = 0; kk < BK; ++kk) {
            float4 a0 = *(const float4*)&AT[kk][tm * 8];
            float4 a1 = *(const float4*)&AT[kk][tm * 8 + 4];
            float4 w  = *(const float4*)&Wt[kk][to * 4];
            acc[0][0] += a0.x * w.x; acc[0][1] += a0.x * w.y; acc[0][2] += a0.x * w.z; acc[0][3] += a0.x * w.w;
            acc[1][0] += a0.y * w.x; acc[1][1] += a0.y * w.y; acc[1][2] += a0.y * w.z; acc[1][3] += a0.y * w.w;
            acc[2][0] += a0.z * w.x; acc[2][1] += a0.z * w.y; acc[2][2] += a0.z * w.z; acc[2][3] += a0.z * w.w;
            acc[3][0] += a0.w * w.x; acc[3][1] += a0.w * w.y; acc[3][2] += a0.w * w.z; acc[3][3] += a0.w * w.w;
            acc[4][0] += a1.x * w.x; acc[4][1] += a1.x * w.y; acc[4][2] += a1.x * w.z; acc[4][3] += a1.x * w.w;
            acc[5][0] += a1.y * w.x; acc[5][1] += a1.y * w.y; acc[5][2] += a1.y * w.z; acc[5][3] += a1.y * w.w;
            acc[6][0] += a1.z * w.x; acc[6][1] += a1.z * w.y; acc[6][2] += a1.z * w.z; acc[6][3] += a1.z * w.w;
            acc[7][0] += a1.w * w.x; acc[7][1] += a1.w * w.y; acc[7][2] += a1.w * w.z; acc[7][3] += a1.w * w.w;
        }
    }

    // epilogue: add bias, store (coalesced float4; reads of agg all done)
    const float4 bb = *(const float4*)(b_l + to * 4);
    #pragma unroll
    for (int n = 0; n < 8; ++n) {
        const int node = base + tm * 8 + n;
        if (node < n_nodes) {
            float4 r = make_float4(acc[n][0] + bb.x, acc[n][1] + bb.y,
                                   acc[n][2] + bb.z, acc[n][3] + bb.w);
            *(float4*)(out + (size_t)node * D + to * 4) = r;
        }
    }
}

// ---------------------------------------------------------------------------
extern "C" void kernel_launch(void* const* d_in, const int* in_sizes, int n_in,
                              void* d_out, int out_size, void* d_ws, size_t ws_size,
                              hipStream_t stream)
{
    const float* x         = (const float*)d_in[0];
    const float* edge_attr = (const float*)d_in[1];
    const float* W_e       = (const float*)d_in[2];
    const float* b_e       = (const float*)d_in[3];
    const float* W_l       = (const float*)d_in[4];
    const float* b_l       = (const float*)d_in[5];
    const float* W_r       = (const float*)d_in[6];
    const void*  edge_index= d_in[7];

    const int n_nodes = in_sizes[0] / D;
    const int n_edges = in_sizes[1] / ED;

    float* out = (float*)d_out;

    // workspace layout (bytes)
    const size_t n_align = ((size_t)n_nodes + 255) & ~(size_t)255;
    const int    NB      = (n_nodes + 255) / 256;       // scan blocks
    const size_t o_flag  = 0;
    const size_t o_cnt   = 512;
    const size_t o_offs  = o_cnt  + n_align * 4;
    const size_t o_cur   = o_offs + n_align * 4;
    const size_t o_bsum  = o_cur  + n_align * 4;
    const size_t o_pair  = (o_bsum + (size_t)NB * 4 + 255) & ~(size_t)255;
    const size_t need    = o_pair + (size_t)n_edges * 8;

    int* flag = (int*)((char*)d_ws + o_flag);

    detect_idx64_kernel<<<1, 256, 0, stream>>>((const int*)edge_index, flag);

    if (need <= ws_size && NB <= 512) {
        int*  cnt    = (int*)((char*)d_ws + o_cnt);
        int*  offs   = (int*)((char*)d_ws + o_offs);
        int*  cursor = (int*)((char*)d_ws + o_cur);
        int*  bsum   = (int*)((char*)d_ws + o_bsum);
        int2* pair   = (int2*)((char*)d_ws + o_pair);

        hipMemsetAsync(cnt, 0, n_align * 4, stream);

        count_kernel<<<2048, 256, 0, stream>>>(edge_index, flag, cnt, n_edges);
        scan1_kernel<<<NB, 256, 0, stream>>>(cnt, offs, bsum, n_nodes);
        scan2_kernel<<<1, 512, 0, stream>>>(bsum, NB);
        scan3_kernel<<<NB, 256, 0, stream>>>(offs, cursor, bsum, n_nodes);
        scatter_kernel<<<2048, 256, 0, stream>>>(edge_index, flag, cursor, pair, n_edges);
        reduce_kernel<<<(n_nodes + 3) / 4, 256, 0, stream>>>(
            x, edge_attr, W_e, b_e, pair, offs, cnt, out, n_nodes);
    } else {
        // fallback: atomic scatter path
        float* cntf = (float*)((char*)d_ws + o_cnt);
        hipMemsetAsync(out, 0, (size_t)out_size * sizeof(float), stream);
        hipMemsetAsync(cntf, 0, (size_t)n_nodes * sizeof(float), stream);
        edge_scatter_kernel<<<4096, 256, 0, stream>>>(
            x, edge_attr, W_e, b_e, edge_index, flag, out, cntf, n_edges);
        divide_kernel<<<(n_nodes * D + 255) / 256, 256, 0, stream>>>(out, cntf, n_nodes);
    }

    node_gemm_kernel<<<(n_nodes + BM - 1) / BM, 256, 0, stream>>>(
        x, out, W_l, b_l, W_r, out, n_nodes);
}